// Round 10
// baseline (16984.666 us; speedup 1.0000x reference)
//
#include <hip/hip_runtime.h>
#include <cmath>

// Batched log(SPD 64x64), one-sided Jacobi with REGISTER-ONLY pair exchange.
// r8 proved the LDS-mirror design sits at the DS-pipe roofline (~2.9ms floor).
// r9/r10: partner-column exchange on the VALU pipe: tv = fv[lane^r] via DPP
// (quad_perm ^1,^2,^3; row_half_mirror ^7; row_mirror ^15) composed with
// permlane16_swap (^16) / permlane32_swap (^32). No LDS in the sweep loop.
// r10 fixes r9's NaN: the permlane*_swap half-select was inverted (even rows
// must take p.y = vsrc', odd rows p.x = vdst').

#define MAXSWEEP 16
#define JTOL 5e-4f
#define XTOL 2e-3f
#define TSTRIDE 68  // floats = 17 float4s -> conflict-free b128 epilogue

typedef float    f32x2 __attribute__((ext_vector_type(2)));
typedef unsigned u32x2 __attribute__((ext_vector_type(2)));

template<int CTRL>
__device__ __forceinline__ float dppf(float x) {
    return __int_as_float(__builtin_amdgcn_update_dpp(
        __float_as_int(x), __float_as_int(x), CTRL, 0xF, 0xF, false));
}
#define DPP_XOR1  dppf<177>   // quad_perm [1,0,3,2]
#define DPP_XOR2  dppf<78>    // quad_perm [2,3,0,1]
#define DPP_XOR3  dppf<27>    // quad_perm [3,2,1,0]
#define DPP_XOR7  dppf<0x141> // row_half_mirror
#define DPP_XOR15 dppf<0x140> // row_mirror

__device__ __forceinline__ int laneid() {
    return __builtin_amdgcn_mbcnt_hi(~0u, __builtin_amdgcn_mbcnt_lo(~0u, 0));
}

// v_permlane16_swap_b32 vdst, vsrc: vdst.row{1,3} <-> vsrc.row{0,2}.
// With vdst=vsrc=x, returns p = {vdst', vsrc'}:
//   p.x rows{1,3} = x rows{0,2} (odd lanes' partner), rows{0,2} = x (own)
//   p.y rows{0,2} = x rows{1,3} (even lanes' partner), rows{1,3} = x (own)
// -> lane wants partner value: odd row takes p.x, even row takes p.y.
#if __has_builtin(__builtin_amdgcn_permlane16_swap)
__device__ __forceinline__ float pswap16(float x, bool oddrow) {
    u32x2 p = __builtin_amdgcn_permlane16_swap(
        (unsigned)__float_as_int(x), (unsigned)__float_as_int(x), false, false);
    return __int_as_float((int)(oddrow ? p.x : p.y));
}
#else
__device__ __forceinline__ float pswap16(float x, bool) {
    return __int_as_float(__builtin_amdgcn_ds_bpermute(
        (laneid() ^ 16) << 2, __float_as_int(x)));
}
#endif
// v_permlane32_swap_b32: vdst lanes[32:64] <-> vsrc lanes[0:32]. Same pattern:
// hi lanes take p.x (= x[lane-32]), lo lanes take p.y (= x[lane+32]).
#if __has_builtin(__builtin_amdgcn_permlane32_swap)
__device__ __forceinline__ float pswap32(float x, bool hihalf) {
    u32x2 p = __builtin_amdgcn_permlane32_swap(
        (unsigned)__float_as_int(x), (unsigned)__float_as_int(x), false, false);
    return __int_as_float((int)(hihalf ? p.x : p.y));
}
#else
__device__ __forceinline__ float pswap32(float x, bool) {
    return __int_as_float(__builtin_amdgcn_ds_bpermute(
        (laneid() ^ 32) << 2, __float_as_int(x)));
}
#endif

// apply one exchange pass to the whole working set (32 f32x2 + 2 scalars)
#define PASS1(FN) do { _Pragma("unroll") \
    for (int i = 0; i < 32; ++i) { tv[i].x = FN(tv[i].x); tv[i].y = FN(tv[i].y); } \
    aqq = FN(aqq); rhoq = FN(rhoq); } while (0)
#define PASS2(FN, HI) do { _Pragma("unroll") \
    for (int i = 0; i < 32; ++i) { tv[i].x = FN(tv[i].x, HI); tv[i].y = FN(tv[i].y, HI); } \
    aqq = FN(aqq, HI); rhoq = FN(rhoq, HI); } while (0)

__global__ __launch_bounds__(64, 2)
void logeig_kernel(const float* __restrict__ X, float* __restrict__ Out, int B)
{
    const int lane = threadIdx.x & 63;
    const long b = blockIdx.x;
    const bool odd16 = (lane & 16) != 0;
    const bool hi32  = (lane & 32) != 0;

    __shared__ float T[64 * TSTRIDE];   // epilogue only

    const float* Xb = X + b * 4096;
    float*       Ob = Out + b * 4096;

    // Column `lane` of X == row `lane` (symmetric) -> contiguous load.
    f32x2 fv[32];
#pragma unroll
    for (int i = 0; i < 16; ++i) {
        const float4 v = reinterpret_cast<const float4*>(Xb + lane * 64)[i];
        fv[2*i+0] = f32x2{v.x, v.y};
        fv[2*i+1] = f32x2{v.z, v.w};
    }

    // unscaled squared column norm (tracked incrementally) + deferred scale rho
    float app;
    {
        f32x2 a0 = {0.f,0.f}, a1 = {0.f,0.f}, a2 = {0.f,0.f}, a3 = {0.f,0.f};
#pragma unroll
        for (int i = 0; i < 32; i += 4) {
            a0 = __builtin_elementwise_fma(fv[i+0], fv[i+0], a0);
            a1 = __builtin_elementwise_fma(fv[i+1], fv[i+1], a1);
            a2 = __builtin_elementwise_fma(fv[i+2], fv[i+2], a2);
            a3 = __builtin_elementwise_fma(fv[i+3], fv[i+3], a3);
        }
        const f32x2 at = (a0 + a1) + (a2 + a3);
        app = at.x + at.y;
    }
    float rho = 1.0f;
    int quiet = 0;

    for (int sweep = 0; sweep < MAXSWEEP; ++sweep) {
        for (int r = 1; r < 64; ++r) {
            const int partner = lane ^ r;

            // ---- register-only exchange: tv = fv from lane^r ----
            // decompose r&15 = m15*15 ^ m7*7 ^ q  (q in 0..3)
            const int  lo  = r & 15;
            const bool m15 = (lo & 8) != 0;
            const int  l4  = m15 ? (lo ^ 15) : lo;
            const bool m7  = (l4 & 4) != 0;
            const int  q   = m7 ? (l4 ^ 7) : l4;

            f32x2 tv[32];
#pragma unroll
            for (int i = 0; i < 32; ++i) tv[i] = fv[i];
            float aqq = app, rhoq = rho;

            if (m15)         PASS1(DPP_XOR15);
            if (m7)          PASS1(DPP_XOR7);
            if (q == 1)      PASS1(DPP_XOR1);
            else if (q == 2) PASS1(DPP_XOR2);
            else if (q == 3) PASS1(DPP_XOR3);
            if (r & 16)      PASS2(pswap16, odd16);
            if (r & 32)      PASS2(pswap32, hi32);
#pragma unroll
            for (int i = 0; i < 32; ++i)
                asm volatile("" : "+v"(tv[i]));   // keep exchanged column live

            // apq: commutative products, identical order on both lanes of the
            // pair -> bit-identical -> identical decisions & angles.
            float apq;
            {
                f32x2 a0 = {0.f,0.f}, a1 = {0.f,0.f}, a2 = {0.f,0.f}, a3 = {0.f,0.f};
#pragma unroll
                for (int i = 0; i < 32; i += 4) {
                    a0 = __builtin_elementwise_fma(fv[i+0], tv[i+0], a0);
                    a1 = __builtin_elementwise_fma(fv[i+1], tv[i+1], a1);
                    a2 = __builtin_elementwise_fma(fv[i+2], tv[i+2], a2);
                    a3 = __builtin_elementwise_fma(fv[i+3], tv[i+3], a3);
                }
                const f32x2 at = (a0 + a1) + (a2 + a3);
                apq = at.x + at.y;
            }

            const float rel  = sqrtf(app * aqq);
            const bool  rot  = fabsf(apq) > JTOL * rel;
            const bool  bigr = __any(fabsf(apq) > XTOL * rel);

            if (__any(rot)) {
                // canonical orientation: p = min-lane, q = max-lane. Pair-shared
                // quantities from commutative products -> bit-identical angles.
                const bool  isp  = lane < partner;
                const float tapp = (rho  * rho ) * app;
                const float taqq = (rhoq * rhoq) * aqq;
                const float prod = (rho * rhoq) * apq;
                const float App = isp ? tapp : taqq;
                const float Aqq = isp ? taqq : tapp;
                const float tau = (Aqq - App) / (2.f * prod);
                const float t0  = copysignf(1.f, tau) / (fabsf(tau) + sqrtf(fmaf(tau, tau, 1.f)));
                const float c0  = rsqrtf(fmaf(t0, t0, 1.f));
                const float tl  = isp ? t0 : -t0;
                const float alpha = rot ? tl * (rhoq * __builtin_amdgcn_rcpf(rho)) : 0.f;

                const f32x2 na = {-alpha, -alpha};
#pragma unroll
                for (int i = 0; i < 32; ++i)
                    fv[i] = __builtin_elementwise_fma(na, tv[i], fv[i]);
                // exact 2x2 identities (guard non-rotating lanes)
                app = rot ? (app - alpha * apq) * fmaf(t0, t0, 1.f) : app;
                rho = rot ? rho * c0 : rho;

                // overflow guard for deferred scaling
                const bool renorm = rot && (app > 1e24f);
                if (__any(renorm)) {
                    const float sc = renorm ? rsqrtf(app) : 1.0f;
                    if (renorm) { rho = rho * (app * sc); app = 1.0f; }
                    const f32x2 sc2 = {sc, sc};
#pragma unroll
                    for (int i = 0; i < 32; ++i) fv[i] = fv[i] * sc2;
                }
            }

            quiet = bigr ? 0 : quiet + 1;
            if (quiet >= 63) break;     // all 63 pairings verified quiet
        }
        if (quiet >= 63) break;
    }

    // ---- epilogue: O = U diag(w) U^T ----
    // lambda = rho*sqrt(nrm2_u); U col = fv/sqrt(nrm2_u) (rho cancels).
    float nrm2;
    {
        f32x2 a0 = {0.f,0.f}, a1 = {0.f,0.f}, a2 = {0.f,0.f}, a3 = {0.f,0.f};
#pragma unroll
        for (int i = 0; i < 32; i += 4) {
            a0 = __builtin_elementwise_fma(fv[i+0], fv[i+0], a0);
            a1 = __builtin_elementwise_fma(fv[i+1], fv[i+1], a1);
            a2 = __builtin_elementwise_fma(fv[i+2], fv[i+2], a2);
            a3 = __builtin_elementwise_fma(fv[i+3], fv[i+3], a3);
        }
        const f32x2 at = (a0 + a1) + (a2 + a3);
        nrm2 = at.x + at.y;
    }
    const float wk  = 0.5f * logf((rho * rho) * nrm2);   // log(lambda)
    const float inv = rsqrtf(nrm2);

    float* myrow = T + lane * TSTRIDE;
#pragma unroll
    for (int i = 0; i < 16; ++i)
        reinterpret_cast<float4*>(myrow)[i] =
            float4{fv[2*i+0].x * inv, fv[2*i+0].y * inv,
                   fv[2*i+1].x * inv, fv[2*i+1].y * inv};  // row lane = u_lane
    myrow[64] = wk;                     // w stored in row padding
    __syncthreads();

    // each lane computes an 8x8 tile of O; O[a][c] = sum_k w_k U[k][a] U[k][c]
    const int la = lane >> 3, lb = lane & 7;
    float acc[8][8];
#pragma unroll
    for (int r0 = 0; r0 < 8; ++r0)
#pragma unroll
        for (int c0 = 0; c0 < 8; ++c0) acc[r0][c0] = 0.f;

#pragma unroll 4
    for (int k = 0; k < 64; ++k) {
        const float wkk = T[k * TSTRIDE + 64];
        const float* row = T + k * TSTRIDE;
        const float4 p0 = *reinterpret_cast<const float4*>(row + la * 8);
        const float4 p1 = *reinterpret_cast<const float4*>(row + la * 8 + 4);
        const float4 u0 = *reinterpret_cast<const float4*>(row + lb * 8);
        const float4 u1 = *reinterpret_cast<const float4*>(row + lb * 8 + 4);
        const float pr[8] = { p0.x*wkk, p0.y*wkk, p0.z*wkk, p0.w*wkk,
                              p1.x*wkk, p1.y*wkk, p1.z*wkk, p1.w*wkk };
        const float uc[8] = { u0.x, u0.y, u0.z, u0.w, u1.x, u1.y, u1.z, u1.w };
#pragma unroll
        for (int r0 = 0; r0 < 8; ++r0)
#pragma unroll
            for (int c0 = 0; c0 < 8; ++c0)
                acc[r0][c0] = fmaf(pr[r0], uc[c0], acc[r0][c0]);
    }

#pragma unroll
    for (int r0 = 0; r0 < 8; ++r0) {
        float* dst = Ob + (la * 8 + r0) * 64 + lb * 8;
        float4 o0 = { acc[r0][0], acc[r0][1], acc[r0][2], acc[r0][3] };
        float4 o1 = { acc[r0][4], acc[r0][5], acc[r0][6], acc[r0][7] };
        reinterpret_cast<float4*>(dst)[0] = o0;
        reinterpret_cast<float4*>(dst)[1] = o1;
    }
}

extern "C" void kernel_launch(void* const* d_in, const int* in_sizes, int n_in,
                              void* d_out, int out_size, void* d_ws, size_t ws_size,
                              hipStream_t stream)
{
    const float* Xp = (const float*)d_in[0];
    float* Op = (float*)d_out;
    const int B = in_sizes[0] / 4096;   // 8192
    logeig_kernel<<<B, 64, 0, stream>>>(Xp, Op, B);
}

// Round 11
// 11421.748 us; speedup vs baseline: 1.4870x; 1.4870x over previous
//
#include <hip/hip_runtime.h>
#include <cmath>

// Batched log(SPD 64x64), one-sided Jacobi with REGISTER-ONLY pair exchange.
// r8 proved the LDS-mirror design sits at the DS-pipe roofline (~2.9ms floor).
// r10 validated correctness of the VALU-pipe exchange (DPP + permlane swaps)
// but spilled tv[] to scratch (85GB writes/dispatch): launch_bounds(64,2) let
// the allocator target 128 VGPRs. r11: launch_bounds(64,1) -> 512-VGPR budget,
// fv+tv+temps (~170) fit in registers; 8 waves/CU (2/SIMD) still saturates
// the VALU pipe. No LDS in the sweep loop (epilogue GEMM only).

#define MAXSWEEP 16
#define JTOL 5e-4f
#define XTOL 2e-3f
#define TSTRIDE 68  // floats = 17 float4s -> conflict-free b128 epilogue

typedef float    f32x2 __attribute__((ext_vector_type(2)));
typedef unsigned u32x2 __attribute__((ext_vector_type(2)));

template<int CTRL>
__device__ __forceinline__ float dppf(float x) {
    return __int_as_float(__builtin_amdgcn_update_dpp(
        __float_as_int(x), __float_as_int(x), CTRL, 0xF, 0xF, false));
}
#define DPP_XOR1  dppf<177>   // quad_perm [1,0,3,2]
#define DPP_XOR2  dppf<78>    // quad_perm [2,3,0,1]
#define DPP_XOR3  dppf<27>    // quad_perm [3,2,1,0]
#define DPP_XOR7  dppf<0x141> // row_half_mirror
#define DPP_XOR15 dppf<0x140> // row_mirror

__device__ __forceinline__ int laneid() {
    return __builtin_amdgcn_mbcnt_hi(~0u, __builtin_amdgcn_mbcnt_lo(~0u, 0));
}

// v_permlane16_swap_b32 vdst, vsrc: vdst.row{1,3} <-> vsrc.row{0,2}.
// With vdst=vsrc=x returns p={vdst',vsrc'}: odd row takes p.x, even takes p.y.
#if __has_builtin(__builtin_amdgcn_permlane16_swap)
__device__ __forceinline__ float pswap16(float x, bool oddrow) {
    u32x2 p = __builtin_amdgcn_permlane16_swap(
        (unsigned)__float_as_int(x), (unsigned)__float_as_int(x), false, false);
    return __int_as_float((int)(oddrow ? p.x : p.y));
}
#else
__device__ __forceinline__ float pswap16(float x, bool) {
    return __int_as_float(__builtin_amdgcn_ds_bpermute(
        (laneid() ^ 16) << 2, __float_as_int(x)));
}
#endif
// v_permlane32_swap_b32: hi half takes p.x, lo half takes p.y.
#if __has_builtin(__builtin_amdgcn_permlane32_swap)
__device__ __forceinline__ float pswap32(float x, bool hihalf) {
    u32x2 p = __builtin_amdgcn_permlane32_swap(
        (unsigned)__float_as_int(x), (unsigned)__float_as_int(x), false, false);
    return __int_as_float((int)(hihalf ? p.x : p.y));
}
#else
__device__ __forceinline__ float pswap32(float x, bool) {
    return __int_as_float(__builtin_amdgcn_ds_bpermute(
        (laneid() ^ 32) << 2, __float_as_int(x)));
}
#endif

// apply one exchange pass to the whole working set (32 f32x2 + 2 scalars)
#define PASS1(FN) do { _Pragma("unroll") \
    for (int i = 0; i < 32; ++i) { tv[i].x = FN(tv[i].x); tv[i].y = FN(tv[i].y); } \
    aqq = FN(aqq); rhoq = FN(rhoq); } while (0)
#define PASS2(FN, HI) do { _Pragma("unroll") \
    for (int i = 0; i < 32; ++i) { tv[i].x = FN(tv[i].x, HI); tv[i].y = FN(tv[i].y, HI); } \
    aqq = FN(aqq, HI); rhoq = FN(rhoq, HI); } while (0)

__global__ __launch_bounds__(64, 1)   // 512-VGPR budget: fv+tv must NOT spill
void logeig_kernel(const float* __restrict__ X, float* __restrict__ Out, int B)
{
    const int lane = threadIdx.x & 63;
    const long b = blockIdx.x;
    const bool odd16 = (lane & 16) != 0;
    const bool hi32  = (lane & 32) != 0;

    __shared__ float T[64 * TSTRIDE];   // epilogue only

    const float* Xb = X + b * 4096;
    float*       Ob = Out + b * 4096;

    // Column `lane` of X == row `lane` (symmetric) -> contiguous load.
    f32x2 fv[32];
#pragma unroll
    for (int i = 0; i < 16; ++i) {
        const float4 v = reinterpret_cast<const float4*>(Xb + lane * 64)[i];
        fv[2*i+0] = f32x2{v.x, v.y};
        fv[2*i+1] = f32x2{v.z, v.w};
    }

    // unscaled squared column norm (tracked incrementally) + deferred scale rho
    float app;
    {
        f32x2 a0 = {0.f,0.f}, a1 = {0.f,0.f}, a2 = {0.f,0.f}, a3 = {0.f,0.f};
#pragma unroll
        for (int i = 0; i < 32; i += 4) {
            a0 = __builtin_elementwise_fma(fv[i+0], fv[i+0], a0);
            a1 = __builtin_elementwise_fma(fv[i+1], fv[i+1], a1);
            a2 = __builtin_elementwise_fma(fv[i+2], fv[i+2], a2);
            a3 = __builtin_elementwise_fma(fv[i+3], fv[i+3], a3);
        }
        const f32x2 at = (a0 + a1) + (a2 + a3);
        app = at.x + at.y;
    }
    float rho = 1.0f;
    int quiet = 0;

    for (int sweep = 0; sweep < MAXSWEEP; ++sweep) {
        for (int r = 1; r < 64; ++r) {
            const int partner = lane ^ r;

            // ---- register-only exchange: tv = fv from lane^r ----
            // decompose r&15 = m15*15 ^ m7*7 ^ q  (q in 0..3)
            const int  lo  = r & 15;
            const bool m15 = (lo & 8) != 0;
            const int  l4  = m15 ? (lo ^ 15) : lo;
            const bool m7  = (l4 & 4) != 0;
            const int  q   = m7 ? (l4 ^ 7) : l4;

            f32x2 tv[32];
#pragma unroll
            for (int i = 0; i < 32; ++i) tv[i] = fv[i];
            float aqq = app, rhoq = rho;

            if (m15)         PASS1(DPP_XOR15);
            if (m7)          PASS1(DPP_XOR7);
            if (q == 1)      PASS1(DPP_XOR1);
            else if (q == 2) PASS1(DPP_XOR2);
            else if (q == 3) PASS1(DPP_XOR3);
            if (r & 16)      PASS2(pswap16, odd16);
            if (r & 32)      PASS2(pswap32, hi32);
#pragma unroll
            for (int i = 0; i < 32; ++i)
                asm("" : "+v"(tv[i]));   // keep exchanged column live (no dup/sink)

            // apq: commutative products, identical order on both lanes of the
            // pair -> bit-identical -> identical decisions & angles.
            float apq;
            {
                f32x2 a0 = {0.f,0.f}, a1 = {0.f,0.f}, a2 = {0.f,0.f}, a3 = {0.f,0.f};
#pragma unroll
                for (int i = 0; i < 32; i += 4) {
                    a0 = __builtin_elementwise_fma(fv[i+0], tv[i+0], a0);
                    a1 = __builtin_elementwise_fma(fv[i+1], tv[i+1], a1);
                    a2 = __builtin_elementwise_fma(fv[i+2], tv[i+2], a2);
                    a3 = __builtin_elementwise_fma(fv[i+3], tv[i+3], a3);
                }
                const f32x2 at = (a0 + a1) + (a2 + a3);
                apq = at.x + at.y;
            }

            const float rel  = sqrtf(app * aqq);
            const bool  rot  = fabsf(apq) > JTOL * rel;
            const bool  bigr = __any(fabsf(apq) > XTOL * rel);

            if (__any(rot)) {
                // canonical orientation: p = min-lane, q = max-lane. Pair-shared
                // quantities from commutative products -> bit-identical angles.
                const bool  isp  = lane < partner;
                const float tapp = (rho  * rho ) * app;
                const float taqq = (rhoq * rhoq) * aqq;
                const float prod = (rho * rhoq) * apq;
                const float App = isp ? tapp : taqq;
                const float Aqq = isp ? taqq : tapp;
                const float tau = (Aqq - App) / (2.f * prod);
                const float t0  = copysignf(1.f, tau) / (fabsf(tau) + sqrtf(fmaf(tau, tau, 1.f)));
                const float c0  = rsqrtf(fmaf(t0, t0, 1.f));
                const float tl  = isp ? t0 : -t0;
                const float alpha = rot ? tl * (rhoq * __builtin_amdgcn_rcpf(rho)) : 0.f;

                const f32x2 na = {-alpha, -alpha};
#pragma unroll
                for (int i = 0; i < 32; ++i)
                    fv[i] = __builtin_elementwise_fma(na, tv[i], fv[i]);
                // exact 2x2 identities (guard non-rotating lanes)
                app = rot ? (app - alpha * apq) * fmaf(t0, t0, 1.f) : app;
                rho = rot ? rho * c0 : rho;

                // overflow guard for deferred scaling
                const bool renorm = rot && (app > 1e24f);
                if (__any(renorm)) {
                    const float sc = renorm ? rsqrtf(app) : 1.0f;
                    if (renorm) { rho = rho * (app * sc); app = 1.0f; }
                    const f32x2 sc2 = {sc, sc};
#pragma unroll
                    for (int i = 0; i < 32; ++i) fv[i] = fv[i] * sc2;
                }
            }

            quiet = bigr ? 0 : quiet + 1;
            if (quiet >= 63) break;     // all 63 pairings verified quiet
        }
        if (quiet >= 63) break;
    }

    // ---- epilogue: O = U diag(w) U^T ----
    // lambda = rho*sqrt(nrm2_u); U col = fv/sqrt(nrm2_u) (rho cancels).
    float nrm2;
    {
        f32x2 a0 = {0.f,0.f}, a1 = {0.f,0.f}, a2 = {0.f,0.f}, a3 = {0.f,0.f};
#pragma unroll
        for (int i = 0; i < 32; i += 4) {
            a0 = __builtin_elementwise_fma(fv[i+0], fv[i+0], a0);
            a1 = __builtin_elementwise_fma(fv[i+1], fv[i+1], a1);
            a2 = __builtin_elementwise_fma(fv[i+2], fv[i+2], a2);
            a3 = __builtin_elementwise_fma(fv[i+3], fv[i+3], a3);
        }
        const f32x2 at = (a0 + a1) + (a2 + a3);
        nrm2 = at.x + at.y;
    }
    const float wk  = 0.5f * logf((rho * rho) * nrm2);   // log(lambda)
    const float inv = rsqrtf(nrm2);

    float* myrow = T + lane * TSTRIDE;
#pragma unroll
    for (int i = 0; i < 16; ++i)
        reinterpret_cast<float4*>(myrow)[i] =
            float4{fv[2*i+0].x * inv, fv[2*i+0].y * inv,
                   fv[2*i+1].x * inv, fv[2*i+1].y * inv};  // row lane = u_lane
    myrow[64] = wk;                     // w stored in row padding
    __syncthreads();

    // each lane computes an 8x8 tile of O; O[a][c] = sum_k w_k U[k][a] U[k][c]
    const int la = lane >> 3, lb = lane & 7;
    float acc[8][8];
#pragma unroll
    for (int r0 = 0; r0 < 8; ++r0)
#pragma unroll
        for (int c0 = 0; c0 < 8; ++c0) acc[r0][c0] = 0.f;

#pragma unroll 4
    for (int k = 0; k < 64; ++k) {
        const float wkk = T[k * TSTRIDE + 64];
        const float* row = T + k * TSTRIDE;
        const float4 p0 = *reinterpret_cast<const float4*>(row + la * 8);
        const float4 p1 = *reinterpret_cast<const float4*>(row + la * 8 + 4);
        const float4 u0 = *reinterpret_cast<const float4*>(row + lb * 8);
        const float4 u1 = *reinterpret_cast<const float4*>(row + lb * 8 + 4);
        const float pr[8] = { p0.x*wkk, p0.y*wkk, p0.z*wkk, p0.w*wkk,
                              p1.x*wkk, p1.y*wkk, p1.z*wkk, p1.w*wkk };
        const float uc[8] = { u0.x, u0.y, u0.z, u0.w, u1.x, u1.y, u1.z, u1.w };
#pragma unroll
        for (int r0 = 0; r0 < 8; ++r0)
#pragma unroll
            for (int c0 = 0; c0 < 8; ++c0)
                acc[r0][c0] = fmaf(pr[r0], uc[c0], acc[r0][c0]);
    }

#pragma unroll
    for (int r0 = 0; r0 < 8; ++r0) {
        float* dst = Ob + (la * 8 + r0) * 64 + lb * 8;
        float4 o0 = { acc[r0][0], acc[r0][1], acc[r0][2], acc[r0][3] };
        float4 o1 = { acc[r0][4], acc[r0][5], acc[r0][6], acc[r0][7] };
        reinterpret_cast<float4*>(dst)[0] = o0;
        reinterpret_cast<float4*>(dst)[1] = o1;
    }
}

extern "C" void kernel_launch(void* const* d_in, const int* in_sizes, int n_in,
                              void* d_out, int out_size, void* d_ws, size_t ws_size,
                              hipStream_t stream)
{
    const float* Xp = (const float*)d_in[0];
    float* Op = (float*)d_out;
    const int B = in_sizes[0] / 4096;   // 8192
    logeig_kernel<<<B, 64, 0, stream>>>(Xp, Op, B);
}

// Round 12
// 3288.557 us; speedup vs baseline: 5.1648x; 3.4732x over previous
//
#include <hip/hip_runtime.h>
#include <cmath>

// Batched log(SPD 64x64), one-sided Jacobi, HYBRID pipe exchange.
// r8: full-DS exchange = DS-pipe issue floor (~320cyc/round, 3.0ms).
// r11: full-VALU (DPP) exchange = VGPR>128 -> <=2 waves/SIMD, 11.4ms.
// r12: per sweep, masks r=1..15 (pure DPP: quad_perm/half/row mirror, 1-2
// passes) run on the VALU pipe with DOUBLE exchange (no tv[] materialized,
// VGPR<128); masks r=16..63 stay on the DS pipe (r6's proven body). One
// dirty-predicated LDS flush per sweep syncs the VALU block's updates.
// DS work/sweep: 63->48 rounds (-23%); added VALU fits in measured headroom.

#define MAXSWEEP 16
#define JTOL 5e-4f
#define XTOL 2e-3f
#define TSTRIDE 68  // floats = 17 float4s (odd) -> conflict-free b128 pattern

typedef float f32x2 __attribute__((ext_vector_type(2)));

template<int CTRL>
__device__ __forceinline__ float dppf(float x) {
    return __int_as_float(__builtin_amdgcn_update_dpp(
        __float_as_int(x), __float_as_int(x), CTRL, 0xF, 0xF, false));
}
// verified on HW in r10 (passed):
#define DPP_XOR1  dppf<177>   // quad_perm [1,0,3,2]
#define DPP_XOR2  dppf<78>    // quad_perm [2,3,0,1]
#define DPP_XOR3  dppf<27>    // quad_perm [3,2,1,0]
#define DPP_XOR7  dppf<0x141> // row_half_mirror
#define DPP_XOR15 dppf<0x140> // row_mirror

// compile-time xor-R exchange for R in 1..15: R = [15] ^ [7] ^ quad
template<int R>
__device__ __forceinline__ float exch_t(float x) {
    if constexpr (R & 8) x = DPP_XOR15(x);
    constexpr int L4 = (R & 8) ? (R ^ 15) : R;
    if constexpr (L4 & 4) x = DPP_XOR7(x);
    constexpr int Q = (L4 & 4) ? (L4 ^ 7) : L4;
    if constexpr (Q == 1) x = DPP_XOR1(x);
    if constexpr (Q == 2) x = DPP_XOR2(x);
    if constexpr (Q == 3) x = DPP_XOR3(x);
    return x;
}
template<int R>
__device__ __forceinline__ f32x2 exch2(f32x2 v) {
    return f32x2{exch_t<R>(v.x), exch_t<R>(v.y)};
}

// One VALU-pipe Jacobi round for uniform mask R (1..15). Double-exchange:
// partner column fetched via DPP during the dot AND again during the update,
// so it never occupies 64 VGPRs. Returns bigr (any pair above XTOL).
template<int R>
__device__ __forceinline__ bool valu_round(f32x2 (&fv)[32], float &app,
                                           float &rho, bool &vdirty, int lane)
{
    float aqq  = exch_t<R>(app);
    float rhoq = exch_t<R>(rho);

    f32x2 a0{0.f,0.f}, a1{0.f,0.f}, a2{0.f,0.f}, a3{0.f,0.f};
#pragma unroll
    for (int i = 0; i < 32; i += 4) {
        const f32x2 t0 = exch2<R>(fv[i+0]);
        const f32x2 t1 = exch2<R>(fv[i+1]);
        const f32x2 t2 = exch2<R>(fv[i+2]);
        const f32x2 t3 = exch2<R>(fv[i+3]);
        a0 = __builtin_elementwise_fma(fv[i+0], t0, a0);
        a1 = __builtin_elementwise_fma(fv[i+1], t1, a1);
        a2 = __builtin_elementwise_fma(fv[i+2], t2, a2);
        a3 = __builtin_elementwise_fma(fv[i+3], t3, a3);
    }
    const f32x2 at = (a0 + a1) + (a2 + a3);
    const float apq = at.x + at.y;     // commutative, same order both lanes

    const float rel  = sqrtf(app * aqq);
    const bool  rot  = fabsf(apq) > JTOL * rel;
    const bool  bigr = __any(fabsf(apq) > XTOL * rel);

    if (__any(rot)) {
        constexpr int HB = (R >= 8) ? 8 : (R >= 4) ? 4 : (R >= 2) ? 2 : 1;
        const bool  isp  = (lane & HB) == 0;        // lane < lane^R
        const float tapp = (rho  * rho ) * app;
        const float taqq = (rhoq * rhoq) * aqq;
        const float prod = (rho * rhoq) * apq;
        const float App = isp ? tapp : taqq;
        const float Aqq = isp ? taqq : tapp;
        const float tau = (Aqq - App) / (2.f * prod);
        const float t0s = copysignf(1.f, tau) / (fabsf(tau) + sqrtf(fmaf(tau, tau, 1.f)));
        const float c0  = rsqrtf(fmaf(t0s, t0s, 1.f));
        const float tl  = isp ? t0s : -t0s;
        const float alpha = rot ? tl * (rhoq * __builtin_amdgcn_rcpf(rho)) : 0.f;
        const f32x2 na = {-alpha, -alpha};
#pragma unroll
        for (int i = 0; i < 32; ++i) {
            // DPP reads partner's pre-update fv[i] (lockstep; per-element WAR
            // dependency orders the exchange before the overwrite)
            const f32x2 t = exch2<R>(fv[i]);
            fv[i] = __builtin_elementwise_fma(na, t, fv[i]);
        }
        app = rot ? (app - alpha * apq) * fmaf(t0s, t0s, 1.f) : app;
        rho = rot ? rho * c0 : rho;

        const bool renorm = rot && (app > 1e24f);
        if (__any(renorm)) {
            const float sc = renorm ? rsqrtf(app) : 1.0f;
            if (renorm) { rho = rho * (app * sc); app = 1.0f; }
            const f32x2 sc2 = {sc, sc};
#pragma unroll
            for (int i = 0; i < 32; ++i) fv[i] = fv[i] * sc2;
        }
        vdirty = vdirty || rot;
    }
    return bigr;
}

__global__ __launch_bounds__(64, 2)
void logeig_kernel(const float* __restrict__ X, float* __restrict__ Out, int B)
{
    const int lane = threadIdx.x & 63;
    const long b = blockIdx.x;

    __shared__ float T[64 * TSTRIDE];   // row k = column k of F; [64..67] pad/w

    const float* Xb = X + b * 4096;
    float*       Ob = Out + b * 4096;
    float4*      myrow = reinterpret_cast<float4*>(T + lane * TSTRIDE);

    // Column `lane` of X == row `lane` (symmetric) -> contiguous load.
    f32x2 fv[32];
#pragma unroll
    for (int i = 0; i < 16; ++i) {
        const float4 v = reinterpret_cast<const float4*>(Xb + lane * 64)[i];
        fv[2*i+0] = f32x2{v.x, v.y};
        fv[2*i+1] = f32x2{v.z, v.w};
        myrow[i] = v;                       // mirror (unscaled) column into LDS
    }
    __builtin_amdgcn_wave_barrier();

    float app;
    {
        f32x2 a0 = {0.f,0.f}, a1 = {0.f,0.f}, a2 = {0.f,0.f}, a3 = {0.f,0.f};
#pragma unroll
        for (int i = 0; i < 32; i += 4) {
            a0 = __builtin_elementwise_fma(fv[i+0], fv[i+0], a0);
            a1 = __builtin_elementwise_fma(fv[i+1], fv[i+1], a1);
            a2 = __builtin_elementwise_fma(fv[i+2], fv[i+2], a2);
            a3 = __builtin_elementwise_fma(fv[i+3], fv[i+3], a3);
        }
        const f32x2 at = (a0 + a1) + (a2 + a3);
        app = at.x + at.y;
    }
    float rho = 1.0f;
    int quiet = 0;
    bool done = false;

    for (int sweep = 0; sweep < MAXSWEEP && !done; ++sweep) {
        // ---- DS-pipe rounds: r = 16..63 (r6's proven body) ----
        for (int r = 16; r < 64; ++r) {
            const int partner = lane ^ r;
            const int pa = partner << 2;

            const float aqq  = __int_as_float(
                __builtin_amdgcn_ds_bpermute(pa, __float_as_int(app)));
            const float rhoq = __int_as_float(
                __builtin_amdgcn_ds_bpermute(pa, __float_as_int(rho)));

            const float4* pc = reinterpret_cast<const float4*>(T + partner * TSTRIDE);
            f32x2 tv[32];
#pragma unroll
            for (int i = 0; i < 16; ++i) {
                const float4 v = pc[i];
                tv[2*i+0] = f32x2{v.x, v.y};
                tv[2*i+1] = f32x2{v.z, v.w};
            }
#pragma unroll
            for (int i = 0; i < 32; ++i)
                asm volatile("" : "+v"(tv[i]));

            float apq;
            {
                f32x2 a0 = {0.f,0.f}, a1 = {0.f,0.f}, a2 = {0.f,0.f}, a3 = {0.f,0.f};
#pragma unroll
                for (int i = 0; i < 32; i += 4) {
                    a0 = __builtin_elementwise_fma(fv[i+0], tv[i+0], a0);
                    a1 = __builtin_elementwise_fma(fv[i+1], tv[i+1], a1);
                    a2 = __builtin_elementwise_fma(fv[i+2], tv[i+2], a2);
                    a3 = __builtin_elementwise_fma(fv[i+3], tv[i+3], a3);
                }
                const f32x2 at = (a0 + a1) + (a2 + a3);
                apq = at.x + at.y;
            }

            const float rel  = sqrtf(app * aqq);
            const bool  rot  = fabsf(apq) > JTOL * rel;
            const bool  bigr = __any(fabsf(apq) > XTOL * rel);

            if (__any(rot)) {
                const bool  isp  = lane < partner;
                const float tapp = (rho  * rho ) * app;
                const float taqq = (rhoq * rhoq) * aqq;
                const float prod = (rho * rhoq) * apq;
                const float App = isp ? tapp : taqq;
                const float Aqq = isp ? taqq : tapp;
                const float tau = (Aqq - App) / (2.f * prod);
                const float t0  = copysignf(1.f, tau) / (fabsf(tau) + sqrtf(fmaf(tau, tau, 1.f)));
                const float c0  = rsqrtf(fmaf(t0, t0, 1.f));
                const float tl  = isp ? t0 : -t0;
                const float alpha = rot ? tl * (rhoq * __builtin_amdgcn_rcpf(rho)) : 0.f;

                const f32x2 na = {-alpha, -alpha};
#pragma unroll
                for (int i = 0; i < 32; ++i)
                    fv[i] = __builtin_elementwise_fma(na, tv[i], fv[i]);
                app = rot ? (app - alpha * apq) * fmaf(t0, t0, 1.f) : app;
                rho = rot ? rho * c0 : rho;

                const bool renorm = rot && (app > 1e24f);
                if (__any(renorm)) {
                    const float sc = renorm ? rsqrtf(app) : 1.0f;
                    if (renorm) { rho = rho * (app * sc); app = 1.0f; }
                    const f32x2 sc2 = {sc, sc};
#pragma unroll
                    for (int i = 0; i < 32; ++i) fv[i] = fv[i] * sc2;
                }

                if (rot) {
#pragma unroll
                    for (int i = 0; i < 16; ++i)
                        myrow[i] = float4{fv[2*i+0].x, fv[2*i+0].y,
                                          fv[2*i+1].x, fv[2*i+1].y};
                }
            }
            __builtin_amdgcn_wave_barrier();

            quiet = bigr ? 0 : quiet + 1;
            if (quiet >= 63) { done = true; break; }
        }

        // ---- VALU-pipe rounds: r = 1..15 (no LDS traffic) ----
        bool vdirty = false;
        if (!done) {
            for (int r = 1; r < 16; ++r) {
                bool bigr;
                switch (r) {
                  case  1: bigr = valu_round< 1>(fv, app, rho, vdirty, lane); break;
                  case  2: bigr = valu_round< 2>(fv, app, rho, vdirty, lane); break;
                  case  3: bigr = valu_round< 3>(fv, app, rho, vdirty, lane); break;
                  case  4: bigr = valu_round< 4>(fv, app, rho, vdirty, lane); break;
                  case  5: bigr = valu_round< 5>(fv, app, rho, vdirty, lane); break;
                  case  6: bigr = valu_round< 6>(fv, app, rho, vdirty, lane); break;
                  case  7: bigr = valu_round< 7>(fv, app, rho, vdirty, lane); break;
                  case  8: bigr = valu_round< 8>(fv, app, rho, vdirty, lane); break;
                  case  9: bigr = valu_round< 9>(fv, app, rho, vdirty, lane); break;
                  case 10: bigr = valu_round<10>(fv, app, rho, vdirty, lane); break;
                  case 11: bigr = valu_round<11>(fv, app, rho, vdirty, lane); break;
                  case 12: bigr = valu_round<12>(fv, app, rho, vdirty, lane); break;
                  case 13: bigr = valu_round<13>(fv, app, rho, vdirty, lane); break;
                  case 14: bigr = valu_round<14>(fv, app, rho, vdirty, lane); break;
                  default: bigr = valu_round<15>(fv, app, rho, vdirty, lane); break;
                }
                quiet = bigr ? 0 : quiet + 1;
                if (quiet >= 63) { done = true; break; }
            }
        }

        // flush VALU-block updates to LDS once per sweep (dirty lanes only)
        if (__any(vdirty)) {
            if (vdirty) {
#pragma unroll
                for (int i = 0; i < 16; ++i)
                    myrow[i] = float4{fv[2*i+0].x, fv[2*i+0].y,
                                      fv[2*i+1].x, fv[2*i+1].y};
            }
        }
        __builtin_amdgcn_wave_barrier();
    }

    // ---- epilogue: O = U diag(w) U^T ----
    float nrm2;
    {
        f32x2 a0 = {0.f,0.f}, a1 = {0.f,0.f}, a2 = {0.f,0.f}, a3 = {0.f,0.f};
#pragma unroll
        for (int i = 0; i < 32; i += 4) {
            a0 = __builtin_elementwise_fma(fv[i+0], fv[i+0], a0);
            a1 = __builtin_elementwise_fma(fv[i+1], fv[i+1], a1);
            a2 = __builtin_elementwise_fma(fv[i+2], fv[i+2], a2);
            a3 = __builtin_elementwise_fma(fv[i+3], fv[i+3], a3);
        }
        const f32x2 at = (a0 + a1) + (a2 + a3);
        nrm2 = at.x + at.y;
    }
    const float wk  = 0.5f * logf((rho * rho) * nrm2);   // log(lambda)
    const float inv = rsqrtf(nrm2);

#pragma unroll
    for (int i = 0; i < 16; ++i)
        myrow[i] = float4{fv[2*i+0].x * inv, fv[2*i+0].y * inv,
                          fv[2*i+1].x * inv, fv[2*i+1].y * inv};  // row lane = u_lane
    T[lane * TSTRIDE + 64] = wk;
    __syncthreads();

    const int la = lane >> 3, lb = lane & 7;
    float acc[8][8];
#pragma unroll
    for (int r0 = 0; r0 < 8; ++r0)
#pragma unroll
        for (int c0 = 0; c0 < 8; ++c0) acc[r0][c0] = 0.f;

#pragma unroll 4
    for (int k = 0; k < 64; ++k) {
        const float wkk = T[k * TSTRIDE + 64];
        const float* row = T + k * TSTRIDE;
        const float4 p0 = *reinterpret_cast<const float4*>(row + la * 8);
        const float4 p1 = *reinterpret_cast<const float4*>(row + la * 8 + 4);
        const float4 u0 = *reinterpret_cast<const float4*>(row + lb * 8);
        const float4 u1 = *reinterpret_cast<const float4*>(row + lb * 8 + 4);
        const float pr[8] = { p0.x*wkk, p0.y*wkk, p0.z*wkk, p0.w*wkk,
                              p1.x*wkk, p1.y*wkk, p1.z*wkk, p1.w*wkk };
        const float uc[8] = { u0.x, u0.y, u0.z, u0.w, u1.x, u1.y, u1.z, u1.w };
#pragma unroll
        for (int r0 = 0; r0 < 8; ++r0)
#pragma unroll
            for (int c0 = 0; c0 < 8; ++c0)
                acc[r0][c0] = fmaf(pr[r0], uc[c0], acc[r0][c0]);
    }

#pragma unroll
    for (int r0 = 0; r0 < 8; ++r0) {
        float* dst = Ob + (la * 8 + r0) * 64 + lb * 8;
        float4 o0 = { acc[r0][0], acc[r0][1], acc[r0][2], acc[r0][3] };
        float4 o1 = { acc[r0][4], acc[r0][5], acc[r0][6], acc[r0][7] };
        reinterpret_cast<float4*>(dst)[0] = o0;
        reinterpret_cast<float4*>(dst)[1] = o1;
    }
}

extern "C" void kernel_launch(void* const* d_in, const int* in_sizes, int n_in,
                              void* d_out, int out_size, void* d_ws, size_t ws_size,
                              hipStream_t stream)
{
    const float* Xp = (const float*)d_in[0];
    float* Op = (float*)d_out;
    const int B = in_sizes[0] / 4096;   // 8192
    logeig_kernel<<<B, 64, 0, stream>>>(Xp, Op, B);
}

// Round 13
// 3263.189 us; speedup vs baseline: 5.2049x; 1.0078x over previous
//
#include <hip/hip_runtime.h>
#include <cmath>

// Batched log(SPD 64x64), one-sided Jacobi, HYBRID pipe exchange, STAGGERED.
// r12 (DS rounds 16..63 + VALU-DPP rounds 1..15) was correct but the VALU
// block sat at the same sweep position in every wave -> DS pipe idled under
// it (+8%). r13: per-block phase offset off in {0,16,32,48} places the VALU
// block at different positions across co-resident waves -> DS pipe stays
// saturated while 1/4 of waves run VALU. Round order within a sweep is
// arbitrary for cyclic Jacobi; quiet-exit (63 consecutive quiet rounds) is
// order-independent. Flush of VALU-rotated columns precedes any later DS read.

#define MAXSWEEP 16
#define JTOL 5e-4f
#define XTOL 2e-3f
#define TSTRIDE 68  // floats = 17 float4s (odd) -> conflict-free b128 pattern

typedef float f32x2 __attribute__((ext_vector_type(2)));

template<int CTRL>
__device__ __forceinline__ float dppf(float x) {
    return __int_as_float(__builtin_amdgcn_update_dpp(
        __float_as_int(x), __float_as_int(x), CTRL, 0xF, 0xF, false));
}
// verified on HW in r10/r12 (passed):
#define DPP_XOR1  dppf<177>   // quad_perm [1,0,3,2]
#define DPP_XOR2  dppf<78>    // quad_perm [2,3,0,1]
#define DPP_XOR3  dppf<27>    // quad_perm [3,2,1,0]
#define DPP_XOR7  dppf<0x141> // row_half_mirror
#define DPP_XOR15 dppf<0x140> // row_mirror

// compile-time xor-R exchange for R in 1..15: R = [15] ^ [7] ^ quad
template<int R>
__device__ __forceinline__ float exch_t(float x) {
    if constexpr (R & 8) x = DPP_XOR15(x);
    constexpr int L4 = (R & 8) ? (R ^ 15) : R;
    if constexpr (L4 & 4) x = DPP_XOR7(x);
    constexpr int Q = (L4 & 4) ? (L4 ^ 7) : L4;
    if constexpr (Q == 1) x = DPP_XOR1(x);
    if constexpr (Q == 2) x = DPP_XOR2(x);
    if constexpr (Q == 3) x = DPP_XOR3(x);
    return x;
}
template<int R>
__device__ __forceinline__ f32x2 exch2(f32x2 v) {
    return f32x2{exch_t<R>(v.x), exch_t<R>(v.y)};
}

// One VALU-pipe Jacobi round for uniform mask R (1..15). Double-exchange:
// partner column fetched via DPP during the dot AND again during the update,
// so it never occupies 64 VGPRs. Returns bigr (any pair above XTOL).
template<int R>
__device__ __forceinline__ bool valu_round(f32x2 (&fv)[32], float &app,
                                           float &rho, bool &vdirty, int lane)
{
    float aqq  = exch_t<R>(app);
    float rhoq = exch_t<R>(rho);

    f32x2 a0{0.f,0.f}, a1{0.f,0.f}, a2{0.f,0.f}, a3{0.f,0.f};
#pragma unroll
    for (int i = 0; i < 32; i += 4) {
        const f32x2 t0 = exch2<R>(fv[i+0]);
        const f32x2 t1 = exch2<R>(fv[i+1]);
        const f32x2 t2 = exch2<R>(fv[i+2]);
        const f32x2 t3 = exch2<R>(fv[i+3]);
        a0 = __builtin_elementwise_fma(fv[i+0], t0, a0);
        a1 = __builtin_elementwise_fma(fv[i+1], t1, a1);
        a2 = __builtin_elementwise_fma(fv[i+2], t2, a2);
        a3 = __builtin_elementwise_fma(fv[i+3], t3, a3);
    }
    const f32x2 at = (a0 + a1) + (a2 + a3);
    const float apq = at.x + at.y;     // commutative, same order both lanes

    const float rel  = sqrtf(app * aqq);
    const bool  rot  = fabsf(apq) > JTOL * rel;
    const bool  bigr = __any(fabsf(apq) > XTOL * rel);

    if (__any(rot)) {
        constexpr int HB = (R >= 8) ? 8 : (R >= 4) ? 4 : (R >= 2) ? 2 : 1;
        const bool  isp  = (lane & HB) == 0;        // lane < lane^R
        const float tapp = (rho  * rho ) * app;
        const float taqq = (rhoq * rhoq) * aqq;
        const float prod = (rho * rhoq) * apq;
        const float App = isp ? tapp : taqq;
        const float Aqq = isp ? taqq : tapp;
        const float tau = (Aqq - App) / (2.f * prod);
        const float t0s = copysignf(1.f, tau) / (fabsf(tau) + sqrtf(fmaf(tau, tau, 1.f)));
        const float c0  = rsqrtf(fmaf(t0s, t0s, 1.f));
        const float tl  = isp ? t0s : -t0s;
        const float alpha = rot ? tl * (rhoq * __builtin_amdgcn_rcpf(rho)) : 0.f;
        const f32x2 na = {-alpha, -alpha};
#pragma unroll
        for (int i = 0; i < 32; ++i) {
            // DPP reads partner's pre-update fv[i] (lockstep; per-element WAR
            // dependency orders the exchange before the overwrite)
            const f32x2 t = exch2<R>(fv[i]);
            fv[i] = __builtin_elementwise_fma(na, t, fv[i]);
        }
        app = rot ? (app - alpha * apq) * fmaf(t0s, t0s, 1.f) : app;
        rho = rot ? rho * c0 : rho;

        const bool renorm = rot && (app > 1e24f);
        if (__any(renorm)) {
            const float sc = renorm ? rsqrtf(app) : 1.0f;
            if (renorm) { rho = rho * (app * sc); app = 1.0f; }
            const f32x2 sc2 = {sc, sc};
#pragma unroll
            for (int i = 0; i < 32; ++i) fv[i] = fv[i] * sc2;
        }
        vdirty = vdirty || rot;
    }
    return bigr;
}

// One DS-pipe Jacobi round for mask r (16..63): r6's proven body.
__device__ __forceinline__ bool ds_round(f32x2 (&fv)[32], float &app,
                                         float &rho, int lane, int r,
                                         const float* T, float4* myrow)
{
    const int partner = lane ^ r;
    const int pa = partner << 2;

    const float aqq  = __int_as_float(
        __builtin_amdgcn_ds_bpermute(pa, __float_as_int(app)));
    const float rhoq = __int_as_float(
        __builtin_amdgcn_ds_bpermute(pa, __float_as_int(rho)));

    const float4* pc = reinterpret_cast<const float4*>(T + partner * TSTRIDE);
    f32x2 tv[32];
#pragma unroll
    for (int i = 0; i < 16; ++i) {
        const float4 v = pc[i];
        tv[2*i+0] = f32x2{v.x, v.y};
        tv[2*i+1] = f32x2{v.z, v.w};
    }
#pragma unroll
    for (int i = 0; i < 32; ++i)
        asm volatile("" : "+v"(tv[i]));

    float apq;
    {
        f32x2 a0 = {0.f,0.f}, a1 = {0.f,0.f}, a2 = {0.f,0.f}, a3 = {0.f,0.f};
#pragma unroll
        for (int i = 0; i < 32; i += 4) {
            a0 = __builtin_elementwise_fma(fv[i+0], tv[i+0], a0);
            a1 = __builtin_elementwise_fma(fv[i+1], tv[i+1], a1);
            a2 = __builtin_elementwise_fma(fv[i+2], tv[i+2], a2);
            a3 = __builtin_elementwise_fma(fv[i+3], tv[i+3], a3);
        }
        const f32x2 at = (a0 + a1) + (a2 + a3);
        apq = at.x + at.y;
    }

    const float rel  = sqrtf(app * aqq);
    const bool  rot  = fabsf(apq) > JTOL * rel;
    const bool  bigr = __any(fabsf(apq) > XTOL * rel);

    if (__any(rot)) {
        const bool  isp  = lane < partner;
        const float tapp = (rho  * rho ) * app;
        const float taqq = (rhoq * rhoq) * aqq;
        const float prod = (rho * rhoq) * apq;
        const float App = isp ? tapp : taqq;
        const float Aqq = isp ? taqq : tapp;
        const float tau = (Aqq - App) / (2.f * prod);
        const float t0  = copysignf(1.f, tau) / (fabsf(tau) + sqrtf(fmaf(tau, tau, 1.f)));
        const float c0  = rsqrtf(fmaf(t0, t0, 1.f));
        const float tl  = isp ? t0 : -t0;
        const float alpha = rot ? tl * (rhoq * __builtin_amdgcn_rcpf(rho)) : 0.f;

        const f32x2 na = {-alpha, -alpha};
#pragma unroll
        for (int i = 0; i < 32; ++i)
            fv[i] = __builtin_elementwise_fma(na, tv[i], fv[i]);
        app = rot ? (app - alpha * apq) * fmaf(t0, t0, 1.f) : app;
        rho = rot ? rho * c0 : rho;

        const bool renorm = rot && (app > 1e24f);
        if (__any(renorm)) {
            const float sc = renorm ? rsqrtf(app) : 1.0f;
            if (renorm) { rho = rho * (app * sc); app = 1.0f; }
            const f32x2 sc2 = {sc, sc};
#pragma unroll
            for (int i = 0; i < 32; ++i) fv[i] = fv[i] * sc2;
        }

        if (rot) {
#pragma unroll
            for (int i = 0; i < 16; ++i)
                myrow[i] = float4{fv[2*i+0].x, fv[2*i+0].y,
                                  fv[2*i+1].x, fv[2*i+1].y};
        }
    }
    __builtin_amdgcn_wave_barrier();
    return bigr;
}

__global__ __launch_bounds__(64, 2)
void logeig_kernel(const float* __restrict__ X, float* __restrict__ Out, int B)
{
    const int lane = threadIdx.x & 63;
    const long b = blockIdx.x;

    __shared__ float T[64 * TSTRIDE];   // row k = column k of F; [64..67] pad/w

    const float* Xb = X + b * 4096;
    float*       Ob = Out + b * 4096;
    float4*      myrow = reinterpret_cast<float4*>(T + lane * TSTRIDE);

    // per-block phase for the VALU block: 0,16,32,48 DS rounds before it.
    // bid ^ (bid>>8) decorrelates from any blockIdx->CU assignment pattern.
    const int off = (int)((blockIdx.x ^ (blockIdx.x >> 8)) & 3) * 16;

    // Column `lane` of X == row `lane` (symmetric) -> contiguous load.
    f32x2 fv[32];
#pragma unroll
    for (int i = 0; i < 16; ++i) {
        const float4 v = reinterpret_cast<const float4*>(Xb + lane * 64)[i];
        fv[2*i+0] = f32x2{v.x, v.y};
        fv[2*i+1] = f32x2{v.z, v.w};
        myrow[i] = v;                       // mirror (unscaled) column into LDS
    }
    __builtin_amdgcn_wave_barrier();

    float app;
    {
        f32x2 a0 = {0.f,0.f}, a1 = {0.f,0.f}, a2 = {0.f,0.f}, a3 = {0.f,0.f};
#pragma unroll
        for (int i = 0; i < 32; i += 4) {
            a0 = __builtin_elementwise_fma(fv[i+0], fv[i+0], a0);
            a1 = __builtin_elementwise_fma(fv[i+1], fv[i+1], a1);
            a2 = __builtin_elementwise_fma(fv[i+2], fv[i+2], a2);
            a3 = __builtin_elementwise_fma(fv[i+3], fv[i+3], a3);
        }
        const f32x2 at = (a0 + a1) + (a2 + a3);
        app = at.x + at.y;
    }
    float rho = 1.0f;
    int quiet = 0;
    bool done = false;

    for (int sweep = 0; sweep < MAXSWEEP && !done; ++sweep) {
        // ---- segment 1: DS masks 16 .. 16+off-1 ----
        for (int r = 16; r < 16 + off && !done; ++r) {
            const bool bigr = ds_round(fv, app, rho, lane, r, T, myrow);
            quiet = bigr ? 0 : quiet + 1;
            if (quiet >= 63) done = true;
        }

        // ---- segment 2: VALU masks 1..15 (no LDS traffic), then flush ----
        if (!done) {
            bool vdirty = false;
            for (int r = 1; r < 16 && !done; ++r) {
                bool bigr;
                switch (r) {
                  case  1: bigr = valu_round< 1>(fv, app, rho, vdirty, lane); break;
                  case  2: bigr = valu_round< 2>(fv, app, rho, vdirty, lane); break;
                  case  3: bigr = valu_round< 3>(fv, app, rho, vdirty, lane); break;
                  case  4: bigr = valu_round< 4>(fv, app, rho, vdirty, lane); break;
                  case  5: bigr = valu_round< 5>(fv, app, rho, vdirty, lane); break;
                  case  6: bigr = valu_round< 6>(fv, app, rho, vdirty, lane); break;
                  case  7: bigr = valu_round< 7>(fv, app, rho, vdirty, lane); break;
                  case  8: bigr = valu_round< 8>(fv, app, rho, vdirty, lane); break;
                  case  9: bigr = valu_round< 9>(fv, app, rho, vdirty, lane); break;
                  case 10: bigr = valu_round<10>(fv, app, rho, vdirty, lane); break;
                  case 11: bigr = valu_round<11>(fv, app, rho, vdirty, lane); break;
                  case 12: bigr = valu_round<12>(fv, app, rho, vdirty, lane); break;
                  case 13: bigr = valu_round<13>(fv, app, rho, vdirty, lane); break;
                  case 14: bigr = valu_round<14>(fv, app, rho, vdirty, lane); break;
                  default: bigr = valu_round<15>(fv, app, rho, vdirty, lane); break;
                }
                quiet = bigr ? 0 : quiet + 1;
                if (quiet >= 63) done = true;
            }
            // flush VALU-rotated columns BEFORE any later DS-round reads them
            if (!done && __any(vdirty)) {
                if (vdirty) {
#pragma unroll
                    for (int i = 0; i < 16; ++i)
                        myrow[i] = float4{fv[2*i+0].x, fv[2*i+0].y,
                                          fv[2*i+1].x, fv[2*i+1].y};
                }
                __builtin_amdgcn_wave_barrier();
            }
        }

        // ---- segment 3: DS masks 16+off .. 63 ----
        for (int r = 16 + off; r < 64 && !done; ++r) {
            const bool bigr = ds_round(fv, app, rho, lane, r, T, myrow);
            quiet = bigr ? 0 : quiet + 1;
            if (quiet >= 63) done = true;
        }
    }

    // ---- epilogue: O = U diag(w) U^T ----
    float nrm2;
    {
        f32x2 a0 = {0.f,0.f}, a1 = {0.f,0.f}, a2 = {0.f,0.f}, a3 = {0.f,0.f};
#pragma unroll
        for (int i = 0; i < 32; i += 4) {
            a0 = __builtin_elementwise_fma(fv[i+0], fv[i+0], a0);
            a1 = __builtin_elementwise_fma(fv[i+1], fv[i+1], a1);
            a2 = __builtin_elementwise_fma(fv[i+2], fv[i+2], a2);
            a3 = __builtin_elementwise_fma(fv[i+3], fv[i+3], a3);
        }
        const f32x2 at = (a0 + a1) + (a2 + a3);
        nrm2 = at.x + at.y;
    }
    const float wk  = 0.5f * logf((rho * rho) * nrm2);   // log(lambda)
    const float inv = rsqrtf(nrm2);

#pragma unroll
    for (int i = 0; i < 16; ++i)
        myrow[i] = float4{fv[2*i+0].x * inv, fv[2*i+0].y * inv,
                          fv[2*i+1].x * inv, fv[2*i+1].y * inv};  // row lane = u_lane
    T[lane * TSTRIDE + 64] = wk;
    __syncthreads();

    const int la = lane >> 3, lb = lane & 7;
    float acc[8][8];
#pragma unroll
    for (int r0 = 0; r0 < 8; ++r0)
#pragma unroll
        for (int c0 = 0; c0 < 8; ++c0) acc[r0][c0] = 0.f;

#pragma unroll 4
    for (int k = 0; k < 64; ++k) {
        const float wkk = T[k * TSTRIDE + 64];
        const float* row = T + k * TSTRIDE;
        const float4 p0 = *reinterpret_cast<const float4*>(row + la * 8);
        const float4 p1 = *reinterpret_cast<const float4*>(row + la * 8 + 4);
        const float4 u0 = *reinterpret_cast<const float4*>(row + lb * 8);
        const float4 u1 = *reinterpret_cast<const float4*>(row + lb * 8 + 4);
        const float pr[8] = { p0.x*wkk, p0.y*wkk, p0.z*wkk, p0.w*wkk,
                              p1.x*wkk, p1.y*wkk, p1.z*wkk, p1.w*wkk };
        const float uc[8] = { u0.x, u0.y, u0.z, u0.w, u1.x, u1.y, u1.z, u1.w };
#pragma unroll
        for (int r0 = 0; r0 < 8; ++r0)
#pragma unroll
            for (int c0 = 0; c0 < 8; ++c0)
                acc[r0][c0] = fmaf(pr[r0], uc[c0], acc[r0][c0]);
    }

#pragma unroll
    for (int r0 = 0; r0 < 8; ++r0) {
        float* dst = Ob + (la * 8 + r0) * 64 + lb * 8;
        float4 o0 = { acc[r0][0], acc[r0][1], acc[r0][2], acc[r0][3] };
        float4 o1 = { acc[r0][4], acc[r0][5], acc[r0][6], acc[r0][7] };
        reinterpret_cast<float4*>(dst)[0] = o0;
        reinterpret_cast<float4*>(dst)[1] = o1;
    }
}

extern "C" void kernel_launch(void* const* d_in, const int* in_sizes, int n_in,
                              void* d_out, int out_size, void* d_ws, size_t ws_size,
                              hipStream_t stream)
{
    const float* Xp = (const float*)d_in[0];
    float* Op = (float*)d_out;
    const int B = in_sizes[0] / 4096;   // 8192
    logeig_kernel<<<B, 64, 0, stream>>>(Xp, Op, B);
}

// Round 14
// 3252.149 us; speedup vs baseline: 5.2226x; 1.0034x over previous
//
#include <hip/hip_runtime.h>
#include <cmath>

// Batched log(SPD 64x64), one-sided Jacobi, LDS-resident columns (r6 champion
// structure) + COMPACT SWIZZLED LDS (r14).
// r6 model: DS pipe ~68% busy, ~32% latency gaps, occupancy capped by LDS
// (17408 B -> 9 blocks/CU). r14: exact-16KB mirror -> 10 blocks/CU (160KiB
// exactly), +25% resident waves to fill the gaps.
// Layout: column k's float4 j-group m lives at f4 slot k*16 + (m ^ (k&7)).
// The XOR reproduces stride-68's +4-bank-per-row stagger: conflict-free for
// own-row b128 writes and partner-row b128 reads (8-lane groups hit start
// banks {0,4,...,28}). w (log-eigenvalues) moved to a per-k ds_bpermute in
// the epilogue instead of LDS padding.

#define MAXSWEEP 16
#define JTOL 2e-4f
#define XTOL 2e-3f

typedef float f32x2 __attribute__((ext_vector_type(2)));

__global__ __launch_bounds__(64, 2)
void logeig_kernel(const float* __restrict__ X, float* __restrict__ Out, int B)
{
    const int lane = threadIdx.x & 63;
    const long b = blockIdx.x;

    __shared__ float T[4096];           // EXACTLY 16 KiB -> 10 blocks/CU
    float4* Tf4 = reinterpret_cast<float4*>(T);

    const float* Xb = X + b * 4096;
    float*       Ob = Out + b * 4096;

    const int myrb = lane * 16;         // own row base (float4 units)
    const int mysw = lane & 7;          // own swizzle

    // Column `lane` of X == row `lane` (symmetric) -> contiguous load.
    f32x2 fv[32];
#pragma unroll
    for (int i = 0; i < 16; ++i) {
        const float4 v = reinterpret_cast<const float4*>(Xb + lane * 64)[i];
        fv[2*i+0] = f32x2{v.x, v.y};
        fv[2*i+1] = f32x2{v.z, v.w};
        Tf4[myrb + (i ^ mysw)] = v;     // mirror column into LDS (swizzled)
    }
    __builtin_amdgcn_wave_barrier();

    // unscaled squared column norm (tracked incrementally) + deferred scale rho
    float app;
    {
        f32x2 a0 = {0.f,0.f}, a1 = {0.f,0.f}, a2 = {0.f,0.f}, a3 = {0.f,0.f};
#pragma unroll
        for (int i = 0; i < 32; i += 4) {
            a0 = __builtin_elementwise_fma(fv[i+0], fv[i+0], a0);
            a1 = __builtin_elementwise_fma(fv[i+1], fv[i+1], a1);
            a2 = __builtin_elementwise_fma(fv[i+2], fv[i+2], a2);
            a3 = __builtin_elementwise_fma(fv[i+3], fv[i+3], a3);
        }
        const f32x2 at = (a0 + a1) + (a2 + a3);
        app = at.x + at.y;
    }
    float rho = 1.0f;

    int quiet = 0;                      // consecutive rounds, all pairs < XTOL
    for (int sweep = 0; sweep < MAXSWEEP; ++sweep) {
        for (int r = 1; r < 64; ++r) {
            // XOR tournament: pair (i,j) meets exactly once per sweep at r=i^j
            const int partner = lane ^ r;
            const int pa = partner << 2;

            const float aqq  = __int_as_float(
                __builtin_amdgcn_ds_bpermute(pa, __float_as_int(app)));
            const float rhoq = __int_as_float(
                __builtin_amdgcn_ds_bpermute(pa, __float_as_int(rho)));

            // fetch partner's (unscaled) column: 16 x ds_read_b128.
            // slot (i ^ psw) holds j-group (i ^ psw) ^ psw = i -> in-order.
            const int pb = partner * 16, psw = partner & 7;
            f32x2 tv[32];
#pragma unroll
            for (int i = 0; i < 16; ++i) {
                const float4 v = Tf4[pb + (i ^ psw)];
                tv[2*i+0] = f32x2{v.x, v.y};
                tv[2*i+1] = f32x2{v.z, v.w};
            }
#pragma unroll
            for (int i = 0; i < 32; ++i)
                asm volatile("" : "+v"(tv[i]));   // pin (avoid re-read)

            // apq: commutative products, identical order on both lanes of the
            // pair -> bit-identical -> identical decisions & angles.
            float apq;
            {
                f32x2 a0 = {0.f,0.f}, a1 = {0.f,0.f}, a2 = {0.f,0.f}, a3 = {0.f,0.f};
#pragma unroll
                for (int i = 0; i < 32; i += 4) {
                    a0 = __builtin_elementwise_fma(fv[i+0], tv[i+0], a0);
                    a1 = __builtin_elementwise_fma(fv[i+1], tv[i+1], a1);
                    a2 = __builtin_elementwise_fma(fv[i+2], tv[i+2], a2);
                    a3 = __builtin_elementwise_fma(fv[i+3], tv[i+3], a3);
                }
                const f32x2 at = (a0 + a1) + (a2 + a3);
                apq = at.x + at.y;
            }

            const float rel  = sqrtf(app * aqq);    // scale-free threshold base
            const bool  rot  = fabsf(apq) > JTOL * rel;
            const bool  bigr = __any(fabsf(apq) > XTOL * rel);

            if (__any(rot)) {
                // canonical orientation: p = min-lane, q = max-lane. Pair-shared
                // quantities from commutative products -> bit-identical angles.
                const bool  isp  = lane < partner;
                const float tapp = (rho  * rho ) * app;   // true ||f_p||^2
                const float taqq = (rhoq * rhoq) * aqq;   // true ||f_q||^2
                const float prod = (rho * rhoq) * apq;    // true <f_p,f_q>
                const float App = isp ? tapp : taqq;
                const float Aqq = isp ? taqq : tapp;
                const float tau = (Aqq - App) / (2.f * prod);
                const float t0  = copysignf(1.f, tau) / (fabsf(tau) + sqrtf(fmaf(tau, tau, 1.f)));
                const float c0  = rsqrtf(fmaf(t0, t0, 1.f));
                const float tl  = isp ? t0 : -t0;         // lane's tangent
                // alpha = tl * rho_q/rho  (unscaled update: fv -= alpha*tv)
                const float alpha = rot ? tl * (rhoq * __builtin_amdgcn_rcpf(rho)) : 0.f;

                const f32x2 na2 = {-alpha, -alpha};
#pragma unroll
                for (int i = 0; i < 32; ++i)
                    fv[i] = __builtin_elementwise_fma(na2, tv[i], fv[i]);

                // exact 2x2 identities (guard non-rotating lanes!)
                app = rot ? (app - alpha * apq) * fmaf(t0, t0, 1.f) : app;
                rho = rot ? rho * c0 : rho;

                // overflow guard for deferred scaling: renormalize rare columns
                const bool renorm = rot && (app > 1e24f);
                if (__any(renorm)) {
                    const float sc = renorm ? rsqrtf(app) : 1.0f;
                    if (renorm) { rho = rho * (app * sc); app = 1.0f; }
                    const f32x2 sc2 = {sc, sc};
#pragma unroll
                    for (int i = 0; i < 32; ++i) fv[i] = fv[i] * sc2;
                }

                if (rot) {  // write updated (unscaled) column back (swizzled)
#pragma unroll
                    for (int i = 0; i < 16; ++i)
                        Tf4[myrb + (i ^ mysw)] =
                            float4{fv[2*i+0].x, fv[2*i+0].y,
                                   fv[2*i+1].x, fv[2*i+1].y};
                }
            }
            __builtin_amdgcn_wave_barrier();

            quiet = bigr ? 0 : quiet + 1;
            if (quiet >= 63) break;     // all 63 pairings verified quiet
        }
        if (quiet >= 63) break;
    }

    // ---- epilogue: O = U diag(w) U^T ----
    // lambda = rho*sqrt(nrm2_u); U col = fv/sqrt(nrm2_u) (rho cancels).
    float nrm2;
    {
        f32x2 a0 = {0.f,0.f}, a1 = {0.f,0.f}, a2 = {0.f,0.f}, a3 = {0.f,0.f};
#pragma unroll
        for (int i = 0; i < 32; i += 4) {
            a0 = __builtin_elementwise_fma(fv[i+0], fv[i+0], a0);
            a1 = __builtin_elementwise_fma(fv[i+1], fv[i+1], a1);
            a2 = __builtin_elementwise_fma(fv[i+2], fv[i+2], a2);
            a3 = __builtin_elementwise_fma(fv[i+3], fv[i+3], a3);
        }
        const f32x2 at = (a0 + a1) + (a2 + a3);
        nrm2 = at.x + at.y;
    }
    const float wk  = 0.5f * logf((rho * rho) * nrm2);   // log(lambda)
    const float inv = rsqrtf(nrm2);

#pragma unroll
    for (int i = 0; i < 16; ++i)
        Tf4[myrb + (i ^ mysw)] =
            float4{fv[2*i+0].x * inv, fv[2*i+0].y * inv,
                   fv[2*i+1].x * inv, fv[2*i+1].y * inv};  // row lane = u_lane
    __syncthreads();

    // each lane computes an 8x8 tile of O; O[a][c] = sum_k w_k U[k][a] U[k][c]
    // w_k fetched per-k via uniform-index ds_bpermute (no LDS storage for w).
    const int la = lane >> 3, lb = lane & 7;
    float acc[8][8];
#pragma unroll
    for (int r0 = 0; r0 < 8; ++r0)
#pragma unroll
        for (int c0 = 0; c0 < 8; ++c0) acc[r0][c0] = 0.f;

#pragma unroll 4
    for (int k = 0; k < 64; ++k) {
        const float wkk = __int_as_float(
            __builtin_amdgcn_ds_bpermute(k << 2, __float_as_int(wk)));
        const int rb = k * 16, ks = k & 7;
        const float4 p0 = Tf4[rb + ((la*2)     ^ ks)];
        const float4 p1 = Tf4[rb + ((la*2 + 1) ^ ks)];
        const float4 u0 = Tf4[rb + ((lb*2)     ^ ks)];
        const float4 u1 = Tf4[rb + ((lb*2 + 1) ^ ks)];
        const float pr[8] = { p0.x*wkk, p0.y*wkk, p0.z*wkk, p0.w*wkk,
                              p1.x*wkk, p1.y*wkk, p1.z*wkk, p1.w*wkk };
        const float uc[8] = { u0.x, u0.y, u0.z, u0.w, u1.x, u1.y, u1.z, u1.w };
#pragma unroll
        for (int r0 = 0; r0 < 8; ++r0)
#pragma unroll
            for (int c0 = 0; c0 < 8; ++c0)
                acc[r0][c0] = fmaf(pr[r0], uc[c0], acc[r0][c0]);
    }

#pragma unroll
    for (int r0 = 0; r0 < 8; ++r0) {
        float* dst = Ob + (la * 8 + r0) * 64 + lb * 8;
        float4 o0 = { acc[r0][0], acc[r0][1], acc[r0][2], acc[r0][3] };
        float4 o1 = { acc[r0][4], acc[r0][5], acc[r0][6], acc[r0][7] };
        reinterpret_cast<float4*>(dst)[0] = o0;
        reinterpret_cast<float4*>(dst)[1] = o1;
    }
}

extern "C" void kernel_launch(void* const* d_in, const int* in_sizes, int n_in,
                              void* d_out, int out_size, void* d_ws, size_t ws_size,
                              hipStream_t stream)
{
    const float* Xp = (const float*)d_in[0];
    float* Op = (float*)d_out;
    const int B = in_sizes[0] / 4096;   // 8192
    logeig_kernel<<<B, 64, 0, stream>>>(Xp, Op, B);
}